// Round 4
// baseline (418.732 us; speedup 1.0000x reference)
//
#include <hip/hip_runtime.h>

#define B_ 32
#define C_ 512
#define HW_ 4096
#define N_ 80
#define HSPLIT 4

typedef __bf16 bf16x8 __attribute__((ext_vector_type(8)));
typedef __bf16 bf16x4 __attribute__((ext_vector_type(4)));
typedef float f32x4 __attribute__((ext_vector_type(4)));
typedef unsigned short u16x8 __attribute__((ext_vector_type(8)));

__device__ __forceinline__ void gload_lds16(const void* g, void* l) {
  __builtin_amdgcn_global_load_lds((const __attribute__((address_space(1))) void*)g,
                                   (__attribute__((address_space(3))) void*)l, 16, 0, 0);
}

// ---------------------------------------------------------------------------
// K0: one-time W f32 -> bf16 (80x512)
// ---------------------------------------------------------------------------
__global__ __launch_bounds__(256) void k0_wconv(const float* __restrict__ W,
                                                __bf16* __restrict__ Wbf) {
  const int i = blockIdx.x * 256 + threadIdx.x;
  if (i < N_ * C_) Wbf[i] = (__bf16)W[i];
}

// ---------------------------------------------------------------------------
// K1: logits[b][n][h] (bf16) = sum_c feats[b][c][h] * W[n][c]
// LDS-staged tile[32 c][128 h] f32 via global_load_lds_dwordx4.
// Block: 4 waves; wave owns [32 h][80 n]. Grid (HW/128, B).
// ---------------------------------------------------------------------------
__global__ __launch_bounds__(256, 4) void k1_logits(const float* __restrict__ feats,
                                                    const __bf16* __restrict__ Wbf,
                                                    __bf16* __restrict__ logits) {
  __shared__ float tile[32][128];  // 16 KB
  const int tid = threadIdx.x;
  const int lane = tid & 63, wave = tid >> 6;
  const int quad = lane >> 4, l16 = lane & 15;
  const int b = blockIdx.y;
  const int htile0 = blockIdx.x * 128;
  const float* fb = feats + (size_t)b * (C_ * HW_);

  const f32x4 zero = {0.f, 0.f, 0.f, 0.f};
  f32x4 acc[2][5];
#pragma unroll
  for (int hf = 0; hf < 2; ++hf)
#pragma unroll
    for (int nf = 0; nf < 5; ++nf) acc[hf][nf] = zero;

  const int scol = (tid & 31) * 4;  // h offset within tile
  const int srow = tid >> 5;        // base c row (rows srow + 8j)

  for (int c0 = 0; c0 < C_; c0 += 32) {
#pragma unroll
    for (int j = 0; j < 4; ++j) {
      const float* gp = fb + (size_t)(c0 + srow + j * 8) * HW_ + htile0 + scol;
      char* lp = (char*)(&tile[0][0]) + j * 4096 + wave * 1024;
      gload_lds16(gp, lp);
    }
    __syncthreads();

    bf16x8 afr[2];
#pragma unroll
    for (int hf = 0; hf < 2; ++hf) {
      const int col = wave * 32 + hf * 16 + l16;
#pragma unroll
      for (int i = 0; i < 8; ++i) afr[hf][i] = (__bf16)tile[quad * 8 + i][col];
    }
#pragma unroll
    for (int nf = 0; nf < 5; ++nf) {
      const u16x8 bv =
          *(const u16x8*)(Wbf + (unsigned)(nf * 16 + l16) * C_ + (unsigned)(c0 + quad * 8));
      const bf16x8 bfr = __builtin_bit_cast(bf16x8, bv);
#pragma unroll
      for (int hf = 0; hf < 2; ++hf)
        acc[hf][nf] =
            __builtin_amdgcn_mfma_f32_16x16x32_bf16(afr[hf], bfr, acc[hf][nf], 0, 0, 0);
    }
    __syncthreads();
  }

#pragma unroll
  for (int nf = 0; nf < 5; ++nf) {
    const int n = nf * 16 + l16;
#pragma unroll
    for (int hf = 0; hf < 2; ++hf) {
      const int h = htile0 + wave * 32 + hf * 16 + quad * 4;
      bf16x4 pk;
#pragma unroll
      for (int j = 0; j < 4; ++j) pk[j] = (__bf16)acc[hf][nf][j];
      *(bf16x4*)(logits + (size_t)(b * N_ + n) * HW_ + h) = pk;
    }
  }
}

// ---------------------------------------------------------------------------
// K2: in-place row softmax over h, NO max-subtraction (logits ~ N(0,1), safe).
// One block per (b,n) row; 256 thr x 16 elems.
// ---------------------------------------------------------------------------
__global__ __launch_bounds__(256) void k2_softmax(__bf16* __restrict__ att) {
  const int tid = threadIdx.x;
  const int lane = tid & 63, wave = tid >> 6;
  __bf16* rp = att + (size_t)blockIdx.x * HW_ + tid * 16;
  const bf16x8 v0 = *(const bf16x8*)(rp);
  const bf16x8 v1 = *(const bf16x8*)(rp + 8);

  float e[16];
  float s = 0.f;
#pragma unroll
  for (int i = 0; i < 8; ++i) {
    e[i] = __expf((float)v0[i]);
    e[i + 8] = __expf((float)v1[i]);
  }
#pragma unroll
  for (int i = 0; i < 16; ++i) s += e[i];
#pragma unroll
  for (int off = 32; off >= 1; off >>= 1) s += __shfl_xor(s, off);

  __shared__ float red[4];
  if (lane == 0) red[wave] = s;
  __syncthreads();
  s = red[0] + red[1] + red[2] + red[3];
  const float r = 1.0f / s;

  bf16x8 o0, o1;
#pragma unroll
  for (int i = 0; i < 8; ++i) {
    o0[i] = (__bf16)(e[i] * r);
    o1[i] = (__bf16)(e[i + 8] * r);
  }
  *(bf16x8*)(rp) = o0;
  *(bf16x8*)(rp + 8) = o1;
}

// ---------------------------------------------------------------------------
// K3: partial[hz][b][n][c] = sum_{h in slice hz} att[b][n][h] * feats[b][c][h]
// Grid (C/64, B, HSPLIT). Launched 3x this round for timing attribution
// (idempotent: pure function of feats+att).
// ---------------------------------------------------------------------------
__global__ __launch_bounds__(256, 4) void k3_pool(const float* __restrict__ feats,
                                                  const __bf16* __restrict__ att,
                                                  float* __restrict__ part) {
  const int tid = threadIdx.x;
  const int lane = tid & 63, wave = tid >> 6;
  const int quad = lane >> 4, l16 = lane & 15;
  const int b = blockIdx.y;
  const int hz = blockIdx.z;
  const int c0 = blockIdx.x * 64 + wave * 16;
  const float* fb = feats + (size_t)b * (C_ * HW_);
  const __bf16* ab = att + (size_t)b * N_ * HW_;
  const unsigned arow = (unsigned)(c0 + l16) * HW_;
  const int hbeg = hz * (HW_ / HSPLIT);
  const int hend = hbeg + (HW_ / HSPLIT);

  const f32x4 zero = {0.f, 0.f, 0.f, 0.f};
  f32x4 acc[5];
#pragma unroll
  for (int nf = 0; nf < 5; ++nf) acc[nf] = zero;

  for (int h0 = hbeg; h0 < hend; h0 += 32) {
    const unsigned hk = (unsigned)(h0 + quad * 8);
    const float4 a0 = *(const float4*)(fb + arow + hk);
    const float4 a1 = *(const float4*)(fb + arow + hk + 4);
    bf16x8 af;
    af[0] = (__bf16)a0.x; af[1] = (__bf16)a0.y; af[2] = (__bf16)a0.z; af[3] = (__bf16)a0.w;
    af[4] = (__bf16)a1.x; af[5] = (__bf16)a1.y; af[6] = (__bf16)a1.z; af[7] = (__bf16)a1.w;
#pragma unroll
    for (int nf = 0; nf < 5; ++nf) {
      const u16x8 bv = *(const u16x8*)(ab + (unsigned)(nf * 16 + l16) * HW_ + hk);
      const bf16x8 bfr = __builtin_bit_cast(bf16x8, bv);
      acc[nf] = __builtin_amdgcn_mfma_f32_16x16x32_bf16(af, bfr, acc[nf], 0, 0, 0);
    }
  }
  float* pb = part + (size_t)hz * (B_ * N_ * C_);
#pragma unroll
  for (int nf = 0; nf < 5; ++nf) {
    const int n = nf * 16 + l16;
    float4 v;
    v.x = acc[nf][0]; v.y = acc[nf][1]; v.z = acc[nf][2]; v.w = acc[nf][3];
    *(float4*)(pb + (size_t)(b * N_ + n) * C_ + c0 + quad * 4) = v;
  }
}

// ---------------------------------------------------------------------------
// K4: out = sum_hz partial[hz]
// ---------------------------------------------------------------------------
__global__ __launch_bounds__(256) void k4_reduce(const float* __restrict__ part,
                                                 float* __restrict__ out) {
  const size_t i = ((size_t)blockIdx.x * 256 + threadIdx.x) * 4;
  if (i >= (size_t)B_ * N_ * C_) return;
  float4 s = *(const float4*)(part + i);
#pragma unroll
  for (int hz = 1; hz < HSPLIT; ++hz) {
    const float4 v = *(const float4*)(part + (size_t)hz * (B_ * N_ * C_) + i);
    s.x += v.x; s.y += v.y; s.z += v.z; s.w += v.w;
  }
  *(float4*)(out + i) = s;
}

extern "C" void kernel_launch(void* const* d_in, const int* in_sizes, int n_in,
                              void* d_out, int out_size, void* d_ws, size_t ws_size,
                              hipStream_t stream) {
  (void)in_sizes; (void)n_in; (void)out_size; (void)ws_size;
  const float* feats = (const float*)d_in[0];
  const float* Wm = (const float*)d_in[1];
  float* out = (float*)d_out;

  __bf16* att = (__bf16*)d_ws;                // 21 MB
  __bf16* Wbf = att + (size_t)B_ * N_ * HW_;  // 80 KB
  float* part = (float*)(Wbf + N_ * C_);      // HSPLIT x 5.24 MB

  hipLaunchKernelGGL(k0_wconv, dim3((N_ * C_ + 255) / 256), dim3(256), 0, stream, Wm, Wbf);
  hipLaunchKernelGGL(k1_logits, dim3(HW_ / 128, B_), dim3(256), 0, stream, feats, Wbf, att);
  hipLaunchKernelGGL(k2_softmax, dim3(B_ * N_), dim3(256), 0, stream, att);
  // Measurement: K3 launched 3x (idempotent). dur' - dur_base = 2 * T_K3.
  hipLaunchKernelGGL(k3_pool, dim3(C_ / 64, B_, HSPLIT), dim3(256), 0, stream, feats, att, part);
  hipLaunchKernelGGL(k3_pool, dim3(C_ / 64, B_, HSPLIT), dim3(256), 0, stream, feats, att, part);
  hipLaunchKernelGGL(k3_pool, dim3(C_ / 64, B_, HSPLIT), dim3(256), 0, stream, feats, att, part);
  const int n4 = (B_ * N_ * C_) / 4;
  hipLaunchKernelGGL(k4_reduce, dim3((n4 + 255) / 256), dim3(256), 0, stream, part, out);
}

// Round 5
// 157.392 us; speedup vs baseline: 2.6604x; 2.6604x over previous
//
#include <hip/hip_runtime.h>

#define B_ 32
#define C_ 512
#define HW_ 4096
#define N_ 80
#define HSPLIT 4

typedef __bf16 bf16x8 __attribute__((ext_vector_type(8)));
typedef __bf16 bf16x4 __attribute__((ext_vector_type(4)));
typedef float f32x4 __attribute__((ext_vector_type(4)));
typedef unsigned short u16x8 __attribute__((ext_vector_type(8)));

__device__ __forceinline__ void gload_lds16(const void* g, void* l) {
  __builtin_amdgcn_global_load_lds((const __attribute__((address_space(1))) void*)g,
                                   (__attribute__((address_space(3))) void*)l, 16, 0, 0);
}

// ---------------------------------------------------------------------------
// K0: one-time W f32 -> bf16 (80x512)
// ---------------------------------------------------------------------------
__global__ __launch_bounds__(256) void k0_wconv(const float* __restrict__ W,
                                                __bf16* __restrict__ Wbf) {
  const int i = blockIdx.x * 256 + threadIdx.x;
  if (i < N_ * C_) Wbf[i] = (__bf16)W[i];
}

// ---------------------------------------------------------------------------
// K1: logits[b][n][h] (bf16) = sum_c feats[b][c][h] * W[n][c]
// (unchanged from R3 — ~69 us; fix K3 first for clean attribution)
// ---------------------------------------------------------------------------
__global__ __launch_bounds__(256, 4) void k1_logits(const float* __restrict__ feats,
                                                    const __bf16* __restrict__ Wbf,
                                                    __bf16* __restrict__ logits) {
  __shared__ float tile[32][128];  // 16 KB
  const int tid = threadIdx.x;
  const int lane = tid & 63, wave = tid >> 6;
  const int quad = lane >> 4, l16 = lane & 15;
  const int b = blockIdx.y;
  const int htile0 = blockIdx.x * 128;
  const float* fb = feats + (size_t)b * (C_ * HW_);

  const f32x4 zero = {0.f, 0.f, 0.f, 0.f};
  f32x4 acc[2][5];
#pragma unroll
  for (int hf = 0; hf < 2; ++hf)
#pragma unroll
    for (int nf = 0; nf < 5; ++nf) acc[hf][nf] = zero;

  const int scol = (tid & 31) * 4;
  const int srow = tid >> 5;

  for (int c0 = 0; c0 < C_; c0 += 32) {
#pragma unroll
    for (int j = 0; j < 4; ++j) {
      const float* gp = fb + (size_t)(c0 + srow + j * 8) * HW_ + htile0 + scol;
      char* lp = (char*)(&tile[0][0]) + j * 4096 + wave * 1024;
      gload_lds16(gp, lp);
    }
    __syncthreads();

    bf16x8 afr[2];
#pragma unroll
    for (int hf = 0; hf < 2; ++hf) {
      const int col = wave * 32 + hf * 16 + l16;
#pragma unroll
      for (int i = 0; i < 8; ++i) afr[hf][i] = (__bf16)tile[quad * 8 + i][col];
    }
#pragma unroll
    for (int nf = 0; nf < 5; ++nf) {
      const u16x8 bv =
          *(const u16x8*)(Wbf + (unsigned)(nf * 16 + l16) * C_ + (unsigned)(c0 + quad * 8));
      const bf16x8 bfr = __builtin_bit_cast(bf16x8, bv);
#pragma unroll
      for (int hf = 0; hf < 2; ++hf)
        acc[hf][nf] =
            __builtin_amdgcn_mfma_f32_16x16x32_bf16(afr[hf], bfr, acc[hf][nf], 0, 0, 0);
    }
    __syncthreads();
  }

#pragma unroll
  for (int nf = 0; nf < 5; ++nf) {
    const int n = nf * 16 + l16;
#pragma unroll
    for (int hf = 0; hf < 2; ++hf) {
      const int h = htile0 + wave * 32 + hf * 16 + quad * 4;
      bf16x4 pk;
#pragma unroll
      for (int j = 0; j < 4; ++j) pk[j] = (__bf16)acc[hf][nf][j];
      *(bf16x4*)(logits + (size_t)(b * N_ + n) * HW_ + h) = pk;
    }
  }
}

// ---------------------------------------------------------------------------
// K2: in-place row softmax over h, no max-subtraction (logits ~ N(0,1)).
// ---------------------------------------------------------------------------
__global__ __launch_bounds__(256) void k2_softmax(__bf16* __restrict__ att) {
  const int tid = threadIdx.x;
  const int lane = tid & 63, wave = tid >> 6;
  __bf16* rp = att + (size_t)blockIdx.x * HW_ + tid * 16;
  const bf16x8 v0 = *(const bf16x8*)(rp);
  const bf16x8 v1 = *(const bf16x8*)(rp + 8);

  float e[16];
  float s = 0.f;
#pragma unroll
  for (int i = 0; i < 8; ++i) {
    e[i] = __expf((float)v0[i]);
    e[i + 8] = __expf((float)v1[i]);
  }
#pragma unroll
  for (int i = 0; i < 16; ++i) s += e[i];
#pragma unroll
  for (int off = 32; off >= 1; off >>= 1) s += __shfl_xor(s, off);

  __shared__ float red[4];
  if (lane == 0) red[wave] = s;
  __syncthreads();
  s = red[0] + red[1] + red[2] + red[3];
  const float r = 1.0f / s;

  bf16x8 o0, o1;
#pragma unroll
  for (int i = 0; i < 8; ++i) {
    o0[i] = (__bf16)(e[i] * r);
    o1[i] = (__bf16)(e[i + 8] * r);
  }
  *(bf16x8*)(rp) = o0;
  *(bf16x8*)(rp + 8) = o1;
}

// ---------------------------------------------------------------------------
// K3-v2: partial[hz][b][n][c] = sum_{h slice} att[b][n][h] * feats[b][c][h]
// LDS-staged GEMM: per 64-h chunk stage feats [64c][64h] f32 (16 KB) and
// att [80n][64h] bf16 (10 KB) via gload_lds with 16B-unit XOR swizzle
// (u' = u ^ (row&7)) applied to the GLOBAL source (LDS dest stays linear).
// Frag ds_read_b128s are conflict-free. Grid (C/64, B, HSPLIT), 4 waves.
// ---------------------------------------------------------------------------
__global__ __launch_bounds__(256, 4) void k3_pool(const float* __restrict__ feats,
                                                  const __bf16* __restrict__ att,
                                                  float* __restrict__ part) {
  __shared__ float fA[64 * 64];   // 16 KB feats tile (swizzled 16B units)
  __shared__ __bf16 fB[80 * 64];  // 10 KB att tile (swizzled 16B units)
  const int tid = threadIdx.x;
  const int lane = tid & 63, w = tid >> 6;
  const int quad = lane >> 4, l16 = lane & 15;
  const int xr = l16 & 7;
  const int b = blockIdx.y, hz = blockIdx.z;
  const int c0 = blockIdx.x * 64;
  const float* fb = feats + (size_t)b * (C_ * HW_);
  const __bf16* ab = att + (size_t)b * N_ * HW_;
  const int hbeg = hz * (HW_ / HSPLIT);
  const int hend = hbeg + (HW_ / HSPLIT);

  const f32x4 zero = {0.f, 0.f, 0.f, 0.f};
  f32x4 acc[5];
#pragma unroll
  for (int nf = 0; nf < 5; ++nf) acc[nf] = zero;

  // staging thread-constants
  const int frow_b = w * 4 + (lane >> 4);  // feats row = j*16 + frow_b
  const int fp = lane & 15;                // feats physical 16B-unit in row
  const int arow_b = w * 8 + (lane >> 3);  // att row = j*32 + arow_b
  const int ap = lane & 7;                 // att physical 16B-unit in row

  for (int h0 = hbeg; h0 < hend; h0 += 64) {
    // ---- stage feats: 4 rounds x (wave: 4 rows x 256B, line-coalesced)
#pragma unroll
    for (int j = 0; j < 4; ++j) {
      const int r = j * 16 + frow_b;
      const int ul = fp ^ (r & 7);  // logical unit held at this physical slot
      const float* gp = fb + (size_t)(c0 + r) * HW_ + h0 + ul * 4;
      gload_lds16(gp, (char*)fA + j * 4096 + w * 1024);
    }
    // ---- stage att: 2.5 rounds x (wave: 8 rows x 128B, line-coalesced)
#pragma unroll
    for (int j = 0; j < 2; ++j) {
      const int r = j * 32 + arow_b;
      const int ul = ap ^ (r & 7);
      const __bf16* gp = ab + (size_t)r * HW_ + h0 + ul * 8;
      gload_lds16(gp, (char*)fB + j * 4096 + w * 1024);
    }
    if (w < 2) {
      const int r = 64 + arow_b;
      const int ul = ap ^ (r & 7);
      const __bf16* gp = ab + (size_t)r * HW_ + h0 + ul * 8;
      gload_lds16(gp, (char*)fB + 8192 + w * 1024);
    }
    __syncthreads();  // compiler drains vmcnt before barrier

#pragma unroll
    for (int s = 0; s < 2; ++s) {
      const int rA = w * 16 + l16;           // c row owned by this lane
      const int g = s * 8 + quad * 2;        // logical 16B-unit (even)
      const f32x4 va = *(const f32x4*)&fA[rA * 64 + ((g ^ xr) << 2)];
      const f32x4 vb = *(const f32x4*)&fA[rA * 64 + (((g + 1) ^ xr) << 2)];
      bf16x8 af;
      af[0] = (__bf16)va[0]; af[1] = (__bf16)va[1];
      af[2] = (__bf16)va[2]; af[3] = (__bf16)va[3];
      af[4] = (__bf16)vb[0]; af[5] = (__bf16)vb[1];
      af[6] = (__bf16)vb[2]; af[7] = (__bf16)vb[3];
      const int uB = (s * 4 + quad) ^ xr;
#pragma unroll
      for (int nf = 0; nf < 5; ++nf) {
        const u16x8 bv = *(const u16x8*)&fB[(nf * 16 + l16) * 64 + uB * 8];
        const bf16x8 bfr = __builtin_bit_cast(bf16x8, bv);
        acc[nf] = __builtin_amdgcn_mfma_f32_16x16x32_bf16(af, bfr, acc[nf], 0, 0, 0);
      }
    }
    __syncthreads();
  }

  // D: row(c) = quad*4 + j, col(n) = l16 -> 4 consecutive c = aligned float4
  float* pb = part + (size_t)hz * (B_ * N_ * C_);
  const int cw = c0 + w * 16;
#pragma unroll
  for (int nf = 0; nf < 5; ++nf) {
    const int n = nf * 16 + l16;
    float4 v;
    v.x = acc[nf][0]; v.y = acc[nf][1]; v.z = acc[nf][2]; v.w = acc[nf][3];
    *(float4*)(pb + (size_t)(b * N_ + n) * C_ + cw + quad * 4) = v;
  }
}

// ---------------------------------------------------------------------------
// K4: out = sum_hz partial[hz]
// ---------------------------------------------------------------------------
__global__ __launch_bounds__(256) void k4_reduce(const float* __restrict__ part,
                                                 float* __restrict__ out) {
  const size_t i = ((size_t)blockIdx.x * 256 + threadIdx.x) * 4;
  if (i >= (size_t)B_ * N_ * C_) return;
  float4 s = *(const float4*)(part + i);
#pragma unroll
  for (int hz = 1; hz < HSPLIT; ++hz) {
    const float4 v = *(const float4*)(part + (size_t)hz * (B_ * N_ * C_) + i);
    s.x += v.x; s.y += v.y; s.z += v.z; s.w += v.w;
  }
  *(float4*)(out + i) = s;
}

extern "C" void kernel_launch(void* const* d_in, const int* in_sizes, int n_in,
                              void* d_out, int out_size, void* d_ws, size_t ws_size,
                              hipStream_t stream) {
  (void)in_sizes; (void)n_in; (void)out_size; (void)ws_size;
  const float* feats = (const float*)d_in[0];
  const float* Wm = (const float*)d_in[1];
  float* out = (float*)d_out;

  __bf16* att = (__bf16*)d_ws;                // 21 MB
  __bf16* Wbf = att + (size_t)B_ * N_ * HW_;  // 80 KB
  float* part = (float*)(Wbf + N_ * C_);      // HSPLIT x 5.24 MB

  hipLaunchKernelGGL(k0_wconv, dim3((N_ * C_ + 255) / 256), dim3(256), 0, stream, Wm, Wbf);
  hipLaunchKernelGGL(k1_logits, dim3(HW_ / 128, B_), dim3(256), 0, stream, feats, Wbf, att);
  hipLaunchKernelGGL(k2_softmax, dim3(B_ * N_), dim3(256), 0, stream, att);
  hipLaunchKernelGGL(k3_pool, dim3(C_ / 64, B_, HSPLIT), dim3(256), 0, stream, feats, att, part);
  const int n4 = (B_ * N_ * C_) / 4;
  hipLaunchKernelGGL(k4_reduce, dim3((n4 + 255) / 256), dim3(256), 0, stream, part, out);
}

// Round 6
// 143.340 us; speedup vs baseline: 2.9213x; 1.0980x over previous
//
#include <hip/hip_runtime.h>

#define B_ 32
#define C_ 512
#define HW_ 4096
#define N_ 80
#define HSPLIT 4

typedef __bf16 bf16x8 __attribute__((ext_vector_type(8)));
typedef __bf16 bf16x4 __attribute__((ext_vector_type(4)));
typedef float f32x4 __attribute__((ext_vector_type(4)));
typedef unsigned short u16x8 __attribute__((ext_vector_type(8)));

__device__ __forceinline__ void gload_lds16(const void* g, void* l) {
  __builtin_amdgcn_global_load_lds((const __attribute__((address_space(1))) void*)g,
                                   (__attribute__((address_space(3))) void*)l, 16, 0, 0);
}

// T3 minimal 2-phase sync: drain own vmem (gload_lds), then raw barrier.
#define WAIT_VM0_BAR()                                  \
  do {                                                  \
    asm volatile("s_waitcnt vmcnt(0)" ::: "memory");    \
    __builtin_amdgcn_s_barrier();                       \
  } while (0)

// ---------------------------------------------------------------------------
// K0: refragment W -> Wfrag bf16. Unit t (16B, 8 c-consecutive bf16):
//   t = (cs*5 + nf)*64 + lane ; holds W[nf*16+(lane&15)][cs*32+(lane>>4)*8 ..+8]
// K1's B-frag load becomes ONE coalesced dwordx4 per (cs,nf) per wave.
// ---------------------------------------------------------------------------
__global__ __launch_bounds__(256) void k0_wfrag(const float* __restrict__ W,
                                                __bf16* __restrict__ Wfrag) {
  const int t = blockIdx.x * 256 + threadIdx.x;
  if (t >= 16 * 5 * 64) return;
  const int cs = t / 320, rem = t % 320;
  const int nf = rem >> 6, lane = rem & 63;
  const int n = nf * 16 + (lane & 15);
  const int c = cs * 32 + (lane >> 4) * 8;
  const float* wp = W + (size_t)n * C_ + c;
  bf16x8 v;
#pragma unroll
  for (int i = 0; i < 8; ++i) v[i] = (__bf16)wp[i];
  *(bf16x8*)(Wfrag + (size_t)t * 8) = v;
}

__global__ __launch_bounds__(256) void kz_zero(float* __restrict__ denom) {
  const int i = blockIdx.x * 256 + threadIdx.x;
  if (i < B_ * N_) denom[i] = 0.f;
}

// ---------------------------------------------------------------------------
// K1: E[b][n][h] = exp( sum_c feats[b][c][h] * W[n][c] )  (bf16 out)
//     denom[b][n] += row partial sums (f32 atomics)
// Double-buffered LDS staging (2 x 16 KB), one barrier per K-step.
// B-frags from Wfrag (coalesced, L1-hot). Grid (HW/128, B), 4 waves.
// ---------------------------------------------------------------------------
__device__ __forceinline__ void k1_stage(const float* fb, float* buf, int cs,
                                         int htile0, int srow, int scol, int wave) {
#pragma unroll
  for (int j = 0; j < 4; ++j) {
    const float* gp = fb + (size_t)(cs * 32 + srow + j * 8) * HW_ + htile0 + scol;
    gload_lds16(gp, (char*)buf + j * 4096 + wave * 1024);
  }
}

__global__ __launch_bounds__(256, 4) void k1_logits(const float* __restrict__ feats,
                                                    const __bf16* __restrict__ Wfrag,
                                                    __bf16* __restrict__ E,
                                                    float* __restrict__ denom) {
  __shared__ float tile[2][32 * 128];  // 2 x 16 KB
  const int tid = threadIdx.x;
  const int lane = tid & 63, wave = tid >> 6;
  const int quad = lane >> 4, l16 = lane & 15;
  const int b = blockIdx.y;
  const int htile0 = blockIdx.x * 128;
  const float* fb = feats + (size_t)b * (C_ * HW_);

  const f32x4 zero = {0.f, 0.f, 0.f, 0.f};
  f32x4 acc[2][5];
#pragma unroll
  for (int hf = 0; hf < 2; ++hf)
#pragma unroll
    for (int nf = 0; nf < 5; ++nf) acc[hf][nf] = zero;

  const int scol = (tid & 31) * 4;
  const int srow = tid >> 5;

  k1_stage(fb, tile[0], 0, htile0, srow, scol, wave);
  WAIT_VM0_BAR();

  for (int cs = 0; cs < 16; ++cs) {
    const int cur = cs & 1;
    if (cs + 1 < 16) k1_stage(fb, tile[cur ^ 1], cs + 1, htile0, srow, scol, wave);

    const float* tb = tile[cur];
    bf16x8 afr[2];
#pragma unroll
    for (int hf = 0; hf < 2; ++hf) {
      const int col = wave * 32 + hf * 16 + l16;
#pragma unroll
      for (int i = 0; i < 8; ++i) afr[hf][i] = (__bf16)tb[(quad * 8 + i) * 128 + col];
    }
#pragma unroll
    for (int nf = 0; nf < 5; ++nf) {
      const u16x8 bv = *(const u16x8*)(Wfrag + ((size_t)(cs * 5 + nf) * 64 + lane) * 8);
      const bf16x8 bfr = __builtin_bit_cast(bf16x8, bv);
#pragma unroll
      for (int hf = 0; hf < 2; ++hf)
        acc[hf][nf] =
            __builtin_amdgcn_mfma_f32_16x16x32_bf16(afr[hf], bfr, acc[hf][nf], 0, 0, 0);
    }
    WAIT_VM0_BAR();  // drains prefetch (overlapped with compute above)
  }

  // Epilogue: e = exp(logit f32), store bf16 E, per-row denom atomics.
#pragma unroll
  for (int nf = 0; nf < 5; ++nf) {
    const int n = nf * 16 + l16;
    float s = 0.f;
#pragma unroll
    for (int hf = 0; hf < 2; ++hf) {
      bf16x4 pk;
#pragma unroll
      for (int j = 0; j < 4; ++j) {
        const float e = __expf(acc[hf][nf][j]);
        s += e;
        pk[j] = (__bf16)e;
      }
      const int h = htile0 + wave * 32 + hf * 16 + quad * 4;
      *(bf16x4*)(E + (size_t)(b * N_ + n) * HW_ + h) = pk;
    }
    s += __shfl_xor(s, 16);
    s += __shfl_xor(s, 32);
    if (lane < 16) atomicAdd(denom + b * N_ + nf * 16 + lane, s);
  }
}

// ---------------------------------------------------------------------------
// K3: part[hz][b][n][c] = sum_{h slice} E[b][n][h] * feats[b][c][h]
// 32-h chunks, double-buffered (2 x 16 KB). XOR source-swizzle (m173):
//   fA [64c][32h] f32, unit p holds logical p^(r&7)  -> b128 reads optimal
//   fB [128n][32h] bf16 (rows 80..127 pad), unit p holds logical p^(r&3)
// Grid (C/64, B, HSPLIT), 4 waves, 4 blocks/CU.
// ---------------------------------------------------------------------------
__device__ __forceinline__ void k3_stage(const float* fb, const __bf16* eb,
                                         float* bufA, __bf16* bufB, int c0, int h0,
                                         int w, int lane) {
#pragma unroll
  for (int j = 0; j < 2; ++j) {
    const int d = j * 256 + w * 64 + lane;
    const int r = d >> 3, p = d & 7;
    const float* gp = fb + (size_t)(c0 + r) * HW_ + h0 + ((p ^ (r & 7)) << 2);
    gload_lds16(gp, (char*)bufA + (j * 256 + w * 64) * 16);
  }
#pragma unroll
  for (int j = 0; j < 2; ++j) {
    const int d = j * 256 + w * 64 + lane;
    const int r = d >> 2, p = d & 3;
    const __bf16* gp = eb + (size_t)r * HW_ + h0 + ((p ^ (r & 3)) << 3);
    gload_lds16(gp, (char*)bufB + (j * 256 + w * 64) * 16);
  }
}

__global__ __launch_bounds__(256, 4) void k3_pool(const float* __restrict__ feats,
                                                  const __bf16* __restrict__ E,
                                                  float* __restrict__ part) {
  __shared__ float fA[2][64 * 32];    // 2 x 8 KB
  __shared__ __bf16 fB[2][128 * 32];  // 2 x 8 KB (rows 80..127 pad, never read)
  const int tid = threadIdx.x;
  const int lane = tid & 63, w = tid >> 6;
  const int quad = lane >> 4, l16 = lane & 15;
  const int b = blockIdx.y, hz = blockIdx.z;
  const int c0 = blockIdx.x * 64;
  const float* fb = feats + (size_t)b * (C_ * HW_);
  const __bf16* eb = E + (size_t)b * N_ * HW_;
  const int hbeg = hz * (HW_ / HSPLIT);

  const f32x4 zero = {0.f, 0.f, 0.f, 0.f};
  f32x4 acc[5];
#pragma unroll
  for (int nf = 0; nf < 5; ++nf) acc[nf] = zero;

  k3_stage(fb, eb, fA[0], fB[0], c0, hbeg, w, lane);
  WAIT_VM0_BAR();

  const int rA = w * 16 + l16;  // this lane's c row
  const int nt = (HW_ / HSPLIT) / 32;
  for (int t = 0; t < nt; ++t) {
    const int cur = t & 1;
    if (t + 1 < nt)
      k3_stage(fb, eb, fA[cur ^ 1], fB[cur ^ 1], c0, hbeg + (t + 1) * 32, w, lane);

    const int u0 = (quad * 2) ^ (rA & 7);
    const int u1 = (quad * 2 + 1) ^ (rA & 7);
    const f32x4 va = *(const f32x4*)&fA[cur][rA * 32 + u0 * 4];
    const f32x4 vb = *(const f32x4*)&fA[cur][rA * 32 + u1 * 4];
    bf16x8 af;
    af[0] = (__bf16)va[0]; af[1] = (__bf16)va[1];
    af[2] = (__bf16)va[2]; af[3] = (__bf16)va[3];
    af[4] = (__bf16)vb[0]; af[5] = (__bf16)vb[1];
    af[6] = (__bf16)vb[2]; af[7] = (__bf16)vb[3];
#pragma unroll
    for (int nf = 0; nf < 5; ++nf) {
      const int rB = nf * 16 + l16;
      const int ub = quad ^ (rB & 3);
      const u16x8 bv = *(const u16x8*)&fB[cur][rB * 32 + ub * 8];
      const bf16x8 bfr = __builtin_bit_cast(bf16x8, bv);
      acc[nf] = __builtin_amdgcn_mfma_f32_16x16x32_bf16(af, bfr, acc[nf], 0, 0, 0);
    }
    WAIT_VM0_BAR();
  }

  float* pb = part + (size_t)hz * (B_ * N_ * C_);
  const int cw = c0 + w * 16;
#pragma unroll
  for (int nf = 0; nf < 5; ++nf) {
    const int n = nf * 16 + l16;
    float4 v;
    v.x = acc[nf][0]; v.y = acc[nf][1]; v.z = acc[nf][2]; v.w = acc[nf][3];
    *(float4*)(pb + (size_t)(b * N_ + n) * C_ + cw + quad * 4) = v;
  }
}

// ---------------------------------------------------------------------------
// K4: out = (sum_hz part[hz]) / denom[b][n]
// ---------------------------------------------------------------------------
__global__ __launch_bounds__(256) void k4_reduce(const float* __restrict__ part,
                                                 const float* __restrict__ denom,
                                                 float* __restrict__ out) {
  const size_t i = ((size_t)blockIdx.x * 256 + threadIdx.x) * 4;
  if (i >= (size_t)B_ * N_ * C_) return;
  float4 s = *(const float4*)(part + i);
#pragma unroll
  for (int hz = 1; hz < HSPLIT; ++hz) {
    const float4 v = *(const float4*)(part + (size_t)hz * (B_ * N_ * C_) + i);
    s.x += v.x; s.y += v.y; s.z += v.z; s.w += v.w;
  }
  const float r = 1.0f / denom[i >> 9];  // i/C_ -> (b*N+n)
  s.x *= r; s.y *= r; s.z *= r; s.w *= r;
  *(float4*)(out + i) = s;
}

extern "C" void kernel_launch(void* const* d_in, const int* in_sizes, int n_in,
                              void* d_out, int out_size, void* d_ws, size_t ws_size,
                              hipStream_t stream) {
  (void)in_sizes; (void)n_in; (void)out_size; (void)ws_size;
  const float* feats = (const float*)d_in[0];
  const float* Wm = (const float*)d_in[1];
  float* out = (float*)d_out;

  __bf16* E = (__bf16*)d_ws;                       // 21 MB
  __bf16* Wfrag = E + (size_t)B_ * N_ * HW_;       // 80 KB
  float* part = (float*)(Wfrag + 16 * 5 * 64 * 8); // HSPLIT x 5.24 MB
  float* denom = part + (size_t)HSPLIT * B_ * N_ * C_;  // 10 KB

  hipLaunchKernelGGL(k0_wfrag, dim3(20), dim3(256), 0, stream, Wm, Wfrag);
  hipLaunchKernelGGL(kz_zero, dim3(10), dim3(256), 0, stream, denom);
  hipLaunchKernelGGL(k1_logits, dim3(HW_ / 128, B_), dim3(256), 0, stream, feats, Wfrag, E, denom);
  hipLaunchKernelGGL(k3_pool, dim3(C_ / 64, B_, HSPLIT), dim3(256), 0, stream, feats, E, part);
  const int n4 = (B_ * N_ * C_) / 4;
  hipLaunchKernelGGL(k4_reduce, dim3(n4 / 256), dim3(256), 0, stream, part, denom, out);
}